// Round 6
// baseline (311.934 us; speedup 1.0000x reference)
//
#include <hip/hip_runtime.h>
#include <hip/hip_bf16.h>

typedef __attribute__((ext_vector_type(8))) short bf16x8;
typedef __attribute__((ext_vector_type(4))) float f32x4;
typedef unsigned short u16;
typedef unsigned int u32;

constexpr int B = 2, S = 2048, D = 2048, H = 16, HD = 128, ROT = 64;
constexpr int NQKV = 3 * D;  // 6144

__device__ __forceinline__ void gload16(const u16* g, u16* l)
{
    __builtin_amdgcn_global_load_lds((const __attribute__((address_space(1))) void*)g,
                                     (__attribute__((address_space(3))) void*)l, 16, 0, 0);
}

__device__ __forceinline__ float bf2f(u32 lo16) { return __uint_as_float(lo16 << 16); }

// ---------------- cast f32 -> bf16 (vectorized) ----------------
__global__ void cast_kernel(const float* __restrict__ in, u16* __restrict__ out, int n4)
{
    int idx = blockIdx.x * blockDim.x + threadIdx.x;
    int stride = gridDim.x * blockDim.x;
    for (int i = idx; i < n4; i += stride) {
        float4 v = ((const float4*)in)[i];
        __hip_bfloat16 a = __float2bfloat16(v.x);
        __hip_bfloat16 b = __float2bfloat16(v.y);
        __hip_bfloat16 c = __float2bfloat16(v.z);
        __hip_bfloat16 d = __float2bfloat16(v.w);
        ushort4 o;
        o.x = *(u16*)&a; o.y = *(u16*)&b; o.z = *(u16*)&c; o.w = *(u16*)&d;
        ((ushort4*)out)[i] = o;
    }
}

// ---------------- fused 4-weight cast ----------------
__global__ void castw_kernel(const float* __restrict__ w0, const float* __restrict__ w1,
                             const float* __restrict__ w2, const float* __restrict__ w3,
                             u16* __restrict__ o0, u16* __restrict__ o1,
                             u16* __restrict__ o2, u16* __restrict__ o3, int n4)
{
    int which = blockIdx.y;
    const float* src = which == 0 ? w0 : which == 1 ? w1 : which == 2 ? w2 : w3;
    u16* dst = which == 0 ? o0 : which == 1 ? o1 : which == 2 ? o2 : o3;
    int idx = blockIdx.x * blockDim.x + threadIdx.x;
    int stride = gridDim.x * blockDim.x;
    for (int i = idx; i < n4; i += stride) {
        float4 v = ((const float4*)src)[i];
        __hip_bfloat16 a = __float2bfloat16(v.x);
        __hip_bfloat16 b = __float2bfloat16(v.y);
        __hip_bfloat16 c = __float2bfloat16(v.z);
        __hip_bfloat16 d = __float2bfloat16(v.w);
        ushort4 o;
        o.x = *(u16*)&a; o.y = *(u16*)&b; o.z = *(u16*)&c; o.w = *(u16*)&d;
        ((ushort4*)dst)[i] = o;
    }
}

// ---------------- prep: rope tables, keep, expo ----------------
__global__ void prep_kernel(const float* __restrict__ mask, const int* __restrict__ pos,
                            const float* __restrict__ ncst,
                            float* __restrict__ sinb, float* __restrict__ cosb,
                            float* __restrict__ keep, float* __restrict__ expo)
{
    int gid = blockIdx.x * blockDim.x + threadIdx.x;
    int total = B * S * 32;
    if (gid < total) {
        int j = gid & 31;
        int bs = gid >> 5;
        float p = (float)pos[bs];
        float f = powf(10000.f, -(float)j / 32.f);
        float ang = p * f;
        sinb[gid] = sinf(ang);
        cosb[gid] = cosf(ang);
        if (j == 0) keep[bs] = (mask[bs] == 0.f) ? 1.f : 0.f;
    }
    if (gid < H) expo[gid] = 1.f / (1.f + expf(-ncst[gid]));
}

// ---------------- counts: inclusive prefix sum of keep per batch ----------------
__global__ void counts_kernel(const float* __restrict__ keep, float* __restrict__ counts)
{
    __shared__ float part[256];
    int b = blockIdx.x, t = threadIdx.x;
    float v[8];
    float s = 0.f;
    const float* kp = keep + b * S + t * 8;
#pragma unroll
    for (int i = 0; i < 8; ++i) { s += kp[i]; v[i] = s; }
    part[t] = s;
    __syncthreads();
    float off = 0.f;
    for (int j = 0; j < t; ++j) off += part[j];
    float* cp = counts + b * S + t * 8;
#pragma unroll
    for (int i = 0; i < 8; ++i) cp[i] = off + v[i];
}

// =======================================================================
// 8-phase 256x256 bf16 B^T GEMM (m201-faithful): derived-wait schedule.
// 512 thr / 8 waves (2M x 4N), BK=64, contiguous half-tiles, XOR swizzle.
// Per iteration (2 K-tiles): 8 phases of {ds_read, stage, bar, lgkm0,
// 16 MFMA, bar}; vmcnt(4) only at P4/P8; stages land in just-freed regions.
// =======================================================================

__device__ __forceinline__ void stage_half(const u16* __restrict__ G, int ldk,
                                           int trow0, int kt, u16* lbuf,
                                           int half, int w, int lane)
{
#pragma unroll
    for (int l = 0; l < 2; ++l) {
        int idx = l * 512 + w * 64 + lane;
        int row = idx >> 3;
        int col8 = (idx & 7) ^ (row & 7);  // inverse-swizzled source (rule 21)
        const u16* g = G + (size_t)(trow0 + half * 128 + row) * ldk + kt * 64 + col8 * 8;
        u16* ld = lbuf + half * 8192 + (size_t)(l * 512 + w * 64) * 8;  // wave-uniform base
        gload16(g, ld);
    }
}

template <int MH>
__device__ __forceinline__ void read_a(const u16* ab, bf16x8 (&af)[4][2], int wm, int l15, int l4)
{
#pragma unroll
    for (int i = 0; i < 4; ++i) {
        int row = MH * 128 + wm * 64 + i * 16 + l15;
#pragma unroll
        for (int ks = 0; ks < 2; ++ks) {
            int slot = (ks * 4 + l4) ^ (row & 7);
            af[i][ks] = *(const bf16x8*)(ab + row * 64 + slot * 8);
        }
    }
}

template <int NH>
__device__ __forceinline__ void read_b(const u16* bb, bf16x8 (&bfr)[2][2], int wn, int l15, int l4)
{
#pragma unroll
    for (int j = 0; j < 2; ++j) {
        int row = NH * 128 + wn * 32 + j * 16 + l15;
#pragma unroll
        for (int ks = 0; ks < 2; ++ks) {
            int slot = (ks * 4 + l4) ^ (row & 7);
            bfr[j][ks] = *(const bf16x8*)(bb + row * 64 + slot * 8);
        }
    }
}

template <int MH, int NH>
__device__ __forceinline__ void mfma_q(const bf16x8 (&af)[4][2], const bf16x8 (&bfr)[2][2],
                                       f32x4 (&acc)[8][4])
{
    __builtin_amdgcn_s_setprio(1);
#pragma unroll
    for (int ks = 0; ks < 2; ++ks)
#pragma unroll
        for (int i = 0; i < 4; ++i)
#pragma unroll
            for (int j = 0; j < 2; ++j)
                acc[MH * 4 + i][NH * 2 + j] = __builtin_amdgcn_mfma_f32_16x16x32_bf16(
                    af[i][ks], bfr[j][ks], acc[MH * 4 + i][NH * 2 + j], 0, 0, 0);
    __builtin_amdgcn_s_setprio(0);
}

#define PH_SYNC() do {                                           \
    __builtin_amdgcn_sched_barrier(0);                           \
    __builtin_amdgcn_s_barrier();                                \
    asm volatile("s_waitcnt lgkmcnt(0)" ::: "memory");           \
    __builtin_amdgcn_sched_barrier(0);                           \
} while (0)

#define PH_END() do {                                            \
    __builtin_amdgcn_sched_barrier(0);                           \
    __builtin_amdgcn_s_barrier();                                \
    __builtin_amdgcn_sched_barrier(0);                           \
} while (0)

template <int BF16OUT>
__global__ __launch_bounds__(512) void gemm8p(
    const u16* __restrict__ A, const u16* __restrict__ Bm,
    float* __restrict__ Cf, u16* __restrict__ Cb, int N, int K, int ntn)
{
    __shared__ u16 As[2][16384];
    __shared__ u16 Bs[2][16384];
    const int tid = threadIdx.x;
    const int lane = tid & 63;
    const int w = tid >> 6;     // 0..7
    const int wm = w >> 2;      // 0..1  (M-half of wave grid)
    const int wn = w & 3;       // 0..3
    const int l15 = lane & 15, l4 = lane >> 4;

    // bijective XCD-aware swizzle (nwg % 8 == 0 for all our grids)
    int nwg = gridDim.x;
    int bid = blockIdx.x;
    int cpx = nwg >> 3;
    int sbid = (bid & 7) * cpx + (bid >> 3);
    int bm = sbid / ntn, bn = sbid % ntn;
    const int bmrow = bm * 256, bnrow = bn * 256;

    u16* A0 = &As[0][0]; u16* B0 = &Bs[0][0];
    u16* A1 = &As[1][0]; u16* B1 = &Bs[1][0];

    f32x4 acc[8][4] = {};
    const int nk = K >> 6;
    const int ni = nk >> 1;

    // prologue: tile0 full into buf0; tile1's h0 pair into buf1
    stage_half(A, K, bmrow, 0, A0, 0, w, lane);
    stage_half(Bm, K, bnrow, 0, B0, 0, w, lane);
    stage_half(A, K, bmrow, 0, A0, 1, w, lane);
    stage_half(Bm, K, bnrow, 0, B0, 1, w, lane);
    stage_half(A, K, bmrow, 1, A1, 0, w, lane);
    stage_half(Bm, K, bnrow, 1, B1, 0, w, lane);
    asm volatile("s_waitcnt vmcnt(4)" ::: "memory");  // certify tile0 (leave t1-h0 pair)
    __builtin_amdgcn_sched_barrier(0);
    __builtin_amdgcn_s_barrier();

    for (int i = 0; i < ni; ++i) {
        const int t1 = 2 * i + 1, t2 = 2 * i + 2, t3 = 2 * i + 3;
        const bool pf = (i + 1 < ni);
        bf16x8 af[4][2], bfr[2][2];

        // ---- P1: Q(0,0) on buf0; stage t1's h1 pair into buf1 ----
        read_a<0>(A0, af, wm, l15, l4);
        read_b<0>(B0, bfr, wn, l15, l4);
        stage_half(A, K, bmrow, t1, A1, 1, w, lane);
        stage_half(Bm, K, bnrow, t1, B1, 1, w, lane);
        PH_SYNC(); mfma_q<0, 0>(af, bfr, acc); PH_END();

        // ---- P2: Q(0,1) (A-h0 frags reused) ----
        read_b<1>(B0, bfr, wn, l15, l4);
        PH_SYNC(); mfma_q<0, 1>(af, bfr, acc); PH_END();

        // ---- P3: Q(1,0); stage A-h0(buf0)<-t2 (freed after P2) ----
        read_a<1>(A0, af, wm, l15, l4);
        read_b<0>(B0, bfr, wn, l15, l4);
        if (pf) stage_half(A, K, bmrow, t2, A0, 0, w, lane);
        PH_SYNC(); mfma_q<1, 0>(af, bfr, acc); PH_END();

        // ---- P4: Q(1,1); stage B-h0(buf0)<-t2 (freed after P3); vmcnt ----
        read_b<1>(B0, bfr, wn, l15, l4);
        if (pf) {
            stage_half(Bm, K, bnrow, t2, B0, 0, w, lane);
            asm volatile("s_waitcnt vmcnt(4)" ::: "memory");  // certify prevP7,prevP8,P1
        } else {
            asm volatile("s_waitcnt vmcnt(0)" ::: "memory");  // tail drain
        }
        PH_SYNC(); mfma_q<1, 1>(af, bfr, acc); PH_END();

        // ---- P5: Q(0,0) on buf1; stage t2's h1 pair into buf0 (freed after P4) ----
        read_a<0>(A1, af, wm, l15, l4);
        read_b<0>(B1, bfr, wn, l15, l4);
        if (pf) {
            stage_half(A, K, bmrow, t2, A0, 1, w, lane);
            stage_half(Bm, K, bnrow, t2, B0, 1, w, lane);
        }
        PH_SYNC(); mfma_q<0, 0>(af, bfr, acc); PH_END();

        // ---- P6: Q(0,1) ----
        read_b<1>(B1, bfr, wn, l15, l4);
        PH_SYNC(); mfma_q<0, 1>(af, bfr, acc); PH_END();

        // ---- P7: Q(1,0); stage A-h0(buf1)<-t3 (freed after P6) ----
        read_a<1>(A1, af, wm, l15, l4);
        read_b<0>(B1, bfr, wn, l15, l4);
        if (pf) stage_half(A, K, bmrow, t3, A1, 0, w, lane);
        PH_SYNC(); mfma_q<1, 0>(af, bfr, acc); PH_END();

        // ---- P8: Q(1,1); stage B-h0(buf1)<-t3 (freed after P7); vmcnt ----
        read_b<1>(B1, bfr, wn, l15, l4);
        if (pf) {
            stage_half(Bm, K, bnrow, t3, B1, 0, w, lane);
            asm volatile("s_waitcnt vmcnt(4)" ::: "memory");  // certify P3,P4,P5 (= tile t2)
        }
        PH_SYNC(); mfma_q<1, 1>(af, bfr, acc); PH_END();
    }

    // epilogue: C-write (col mapping matches contiguous NH halves)
#pragma unroll
    for (int MH = 0; MH < 2; ++MH)
#pragma unroll
        for (int i = 0; i < 4; ++i) {
            int row = bmrow + MH * 128 + wm * 64 + i * 16 + l4 * 4;
#pragma unroll
            for (int NH = 0; NH < 2; ++NH)
#pragma unroll
                for (int j = 0; j < 2; ++j) {
                    int col = bnrow + NH * 128 + wn * 32 + j * 16 + l15;
                    f32x4 v = acc[MH * 4 + i][NH * 2 + j];
#pragma unroll
                    for (int r = 0; r < 4; ++r) {
                        if (BF16OUT) {
                            __hip_bfloat16 hv = __float2bfloat16(v[r]);
                            Cb[(size_t)(row + r) * N + col] = *(u16*)&hv;
                        } else {
                            Cf[(size_t)(row + r) * N + col] = v[r];
                        }
                    }
                }
        }
}

// ---------------- fused postproc: RoPE + norm (q,k), count-scale (v) ----------------
__global__ void postproc_all(const u16* __restrict__ tmpb,
                             u16* __restrict__ qn, u16* __restrict__ kn, u16* __restrict__ vT,
                             const float* __restrict__ sinb, const float* __restrict__ cosb,
                             const float* __restrict__ keep, const float* __restrict__ counts,
                             const float* __restrict__ expo)
{
    int gw = (blockIdx.x * blockDim.x + threadIdx.x) >> 6;
    int lane = threadIdx.x & 63;
    if (gw >= B * S * H) return;
    int h = gw % H;
    int sb = gw / H;
    int s = sb % S;
    int b = sb / S;
    const u16* rowp = tmpb + (size_t)(b * S + s) * NQKV;
    u32 qv = *(const u32*)(rowp + h * 128 + lane * 2);
    u32 kv = *(const u32*)(rowp + D + h * 128 + lane * 2);
    u32 vv = *(const u32*)(rowp + 2 * D + h * 128 + lane * 2);
    float q0 = bf2f(qv & 0xffff), q1 = bf2f(qv >> 16);
    float k0 = bf2f(kv & 0xffff), k1 = bf2f(kv >> 16);
    float v0 = bf2f(vv & 0xffff), v1 = bf2f(vv >> 16);
    if (lane < 32) {
        float sn = sinb[(b * S + s) * 32 + lane];
        float cs = cosb[(b * S + s) * 32 + lane];
        float nq0 = q0 * cs - q1 * sn, nq1 = q1 * cs + q0 * sn;
        float nk0 = k0 * cs - k1 * sn, nk1 = k1 * cs + k0 * sn;
        q0 = nq0; q1 = nq1; k0 = nk0; k1 = nk1;
    }
    float sq = q0 * q0 + q1 * q1;
    float sk = k0 * k0 + k1 * k1;
#pragma unroll
    for (int o = 1; o < 64; o <<= 1) {
        sq += __shfl_xor(sq, o, 64);
        sk += __shfl_xor(sk, o, 64);
    }
    float kf = keep[b * S + s];
    float scq = kf / fmaxf(sqrtf(sq), 1e-12f);
    float sck = kf / fmaxf(sqrtf(sk), 1e-12f);
    float cnt = counts[b * S + s];
    float e = expo[h];
    float scv = kf / fmaxf(powf(cnt, e), 1.0f);

    __hip_bfloat16 a0 = __float2bfloat16(q0 * scq), a1 = __float2bfloat16(q1 * scq);
    __hip_bfloat16 b0 = __float2bfloat16(k0 * sck), b1 = __float2bfloat16(k1 * sck);
    __hip_bfloat16 c0 = __float2bfloat16(v0 * scv), c1 = __float2bfloat16(v1 * scv);
    size_t obase = ((size_t)(b * H + h) * S + s) * 128 + lane * 2;
    *(u32*)(qn + obase) = (u32)*(u16*)&a0 | ((u32)*(u16*)&a1 << 16);
    *(u32*)(kn + obase) = (u32)*(u16*)&b0 | ((u32)*(u16*)&b1 << 16);
    size_t vbase = ((size_t)(b * H + h) * 128) * (size_t)S + s;
    vT[vbase + (size_t)(2 * lane) * S] = *(u16*)&c0;
    vT[vbase + (size_t)(2 * lane + 1) * S] = *(u16*)&c1;
}

// ---------------- chunk state: T_c[d][d'] = sum_{k in chunk} v[k,d] * kn[k,d'] ----------------
__global__ __launch_bounds__(256) void chunk_state(
    const u16* __restrict__ kn, const u16* __restrict__ vT, u16* __restrict__ T16)
{
    __shared__ u16 As[128][72];
    __shared__ u16 Bs[128][72];
    int tid = threadIdx.x, lane = tid & 63, w = tid >> 6;
    int wm = w >> 1, wn = w & 1;
    int c = blockIdx.x, bh = blockIdx.y;
    const int l15 = lane & 15, l4 = lane >> 4;
    size_t vbase = (size_t)bh * 128 * S;
    size_t kbase = (size_t)bh * S * 128;
    f32x4 acc[4][4] = {};

    for (int t = 0; t < 2; ++t) {
#pragma unroll
        for (int i = 0; i < 4; ++i) {
            int q = tid + i * 256;
            int r = q >> 3, c8 = q & 7;
            uint4 v = *(const uint4*)(vT + vbase + (size_t)r * S + c * 128 + t * 64 + c8 * 8);
            *(uint4*)(&As[r][c8 * 8]) = v;
        }
#pragma unroll
        for (int i = 0; i < 4; ++i) {
            int q = tid + i * 256;
            int r = q >> 4, c16 = q & 15;
            uint4 v = *(const uint4*)(kn + kbase + (size_t)(c * 128 + t * 64 + r) * 128 + c16 * 8);
            const u16* pv = (const u16*)&v;
#pragma unroll
            for (int j = 0; j < 8; ++j) Bs[c16 * 8 + j][r] = pv[j];
        }
        __syncthreads();
#pragma unroll
        for (int tt = 0; tt < 2; ++tt) {
            bf16x8 a[4], b[4];
#pragma unroll
            for (int m = 0; m < 4; ++m)
                a[m] = *(const bf16x8*)(&As[wm * 64 + m * 16 + l15][tt * 32 + l4 * 8]);
#pragma unroll
            for (int n = 0; n < 4; ++n)
                b[n] = *(const bf16x8*)(&Bs[wn * 64 + n * 16 + l15][tt * 32 + l4 * 8]);
#pragma unroll
            for (int m = 0; m < 4; ++m)
#pragma unroll
                for (int n = 0; n < 4; ++n)
                    acc[m][n] = __builtin_amdgcn_mfma_f32_16x16x32_bf16(a[m], b[n], acc[m][n], 0, 0, 0);
        }
        __syncthreads();
    }
#pragma unroll
    for (int m = 0; m < 4; ++m) {
        int row = wm * 64 + m * 16 + l4 * 4;
#pragma unroll
        for (int n = 0; n < 4; ++n) {
            int col = wn * 64 + n * 16 + l15;
#pragma unroll
            for (int r = 0; r < 4; ++r) {
                __hip_bfloat16 hv = __float2bfloat16(acc[m][n][r]);
                T16[((size_t)(bh * 16 + c) * 128 + row + r) * 128 + col] = *(u16*)&hv;
            }
        }
    }
}

// ---------------- exclusive prefix over chunks: P_c = sum_{c'<c} T_c' ----------------
__global__ void prefix_state(const u16* __restrict__ T16, u16* __restrict__ P16)
{
    int g = blockIdx.x * blockDim.x + threadIdx.x;
    int bh = g >> 11;
    int i8 = (g & 2047) * 8;
    const u16* tp = T16 + (size_t)bh * 16 * 16384 + i8;
    u16* pp = P16 + (size_t)bh * 16 * 16384 + i8;
    float run[8] = {};
    for (int c = 0; c < 16; ++c) {
        u16 ob[8];
#pragma unroll
        for (int j = 0; j < 8; ++j) { __hip_bfloat16 hv = __float2bfloat16(run[j]); ob[j] = *(u16*)&hv; }
        *(uint4*)(pp + (size_t)c * 16384) = *(uint4*)ob;
        uint4 tv = *(const uint4*)(tp + (size_t)c * 16384);
        const u16* tvp = (const u16*)&tv;
#pragma unroll
        for (int j = 0; j < 8; ++j) run[j] += bf2f(tvp[j]);
    }
}

// ---------------- chunked attention: out_c = qn_c . P_c + causal_intra ----------------
__global__ __launch_bounds__(256, 2) void attn2(
    const u16* __restrict__ qn, const u16* __restrict__ kn,
    const u16* __restrict__ vT, const u16* __restrict__ P16, u16* __restrict__ ao)
{
    __shared__ u16 KN[64][136];
    __shared__ u16 VT[128][72];
    __shared__ u16 SC[128][72];
    int tid = threadIdx.x, lane = tid & 63, w = tid >> 6;
    int c = blockIdx.x, bh = blockIdx.y;
    int b = bh >> 4, h = bh & 15;
    const int l15 = lane & 15, l4 = lane >> 4;
    size_t base = (size_t)bh * S * 128;
    size_t vbase = (size_t)bh * 128 * S;
    const u16* Pp = P16 + (size_t)(bh * 16 + c) * 16384;

    bf16x8 qa[2][4];
#pragma unroll
    for (int m = 0; m < 2; ++m)
#pragma unroll
        for (int t = 0; t < 4; ++t) {
            int row = c * 128 + w * 32 + m * 16 + l15;
            qa[m][t] = *(const bf16x8*)(qn + base + (size_t)row * 128 + t * 32 + l4 * 8);
        }

    f32x4 acc[2][8] = {};

#pragma unroll
    for (int pt = 0; pt < 2; ++pt) {
#pragma unroll
        for (int i = 0; i < 4; ++i) {
            int q = tid + i * 256;
            int r = q >> 3, c8 = q & 7;
            uint4 v = *(const uint4*)(Pp + (size_t)r * 128 + pt * 64 + c8 * 8);
            *(uint4*)(&VT[r][c8 * 8]) = v;
        }
        __syncthreads();
#pragma unroll
        for (int tt = 0; tt < 2; ++tt) {
            bf16x8 pb[8];
#pragma unroll
            for (int n = 0; n < 8; ++n)
                pb[n] = *(const bf16x8*)(&VT[n * 16 + l15][tt * 32 + l4 * 8]);
#pragma unroll
            for (int m = 0; m < 2; ++m)
#pragma unroll
                for (int n = 0; n < 8; ++n)
                    acc[m][n] = __builtin_amdgcn_mfma_f32_16x16x32_bf16(qa[m][pt * 2 + tt], pb[n], acc[m][n], 0, 0, 0);
        }
        __syncthreads();
    }

    for (int kt2 = 0; kt2 < 2; ++kt2) {
#pragma unroll
        for (int i = 0; i < 4; ++i) {
            int q = tid + i * 256;
            int r = q >> 4, c8 = q & 15;
            uint4 v = *(const uint4*)(kn + base + (size_t)(c * 128 + kt2 * 64 + r) * 128 + c8 * 8);
            *(uint4*)(&KN[r][c8 * 8]) = v;
        }
#pragma unroll
        for (int i = 0; i < 4; ++i) {
            int q = tid + i * 256;
            int r = q >> 3, c8 = q & 7;
            uint4 v = *(const uint4*)(vT + vbase + (size_t)r * S + c * 128 + kt2 * 64 + c8 * 8);
            *(uint4*)(&VT[r][c8 * 8]) = v;
        }
        __syncthreads();
        f32x4 sacc[2][4] = {};
#pragma unroll
        for (int t = 0; t < 4; ++t) {
            bf16x8 kb[4];
#pragma unroll
            for (int n = 0; n < 4; ++n)
                kb[n] = *(const bf16x8*)(&KN[n * 16 + l15][t * 32 + l4 * 8]);
#pragma unroll
            for (int m = 0; m < 2; ++m)
#pragma unroll
                for (int n = 0; n < 4; ++n)
                    sacc[m][n] = __builtin_amdgcn_mfma_f32_16x16x32_bf16(qa[m][t], kb[n], sacc[m][n], 0, 0, 0);
        }
#pragma unroll
        for (int m = 0; m < 2; ++m)
#pragma unroll
            for (int n = 0; n < 4; ++n)
#pragma unroll
                for (int r = 0; r < 4; ++r) {
                    int rowl = w * 32 + m * 16 + l4 * 4 + r;
                    int coll = n * 16 + l15;
                    int kl = kt2 * 64 + coll;
                    float val = (kl <= rowl) ? sacc[m][n][r] : 0.f;
                    __hip_bfloat16 hv = __float2bfloat16(val);
                    SC[rowl][coll] = *(u16*)&hv;
                }
#pragma unroll
        for (int t = 0; t < 2; ++t) {
            bf16x8 sa[2], vb[8];
#pragma unroll
            for (int m = 0; m < 2; ++m)
                sa[m] = *(const bf16x8*)(&SC[w * 32 + m * 16 + l15][t * 32 + l4 * 8]);
#pragma unroll
            for (int n = 0; n < 8; ++n)
                vb[n] = *(const bf16x8*)(&VT[n * 16 + l15][t * 32 + l4 * 8]);
#pragma unroll
            for (int m = 0; m < 2; ++m)
#pragma unroll
                for (int n = 0; n < 8; ++n)
                    acc[m][n] = __builtin_amdgcn_mfma_f32_16x16x32_bf16(sa[m], vb[n], acc[m][n], 0, 0, 0);
        }
        __syncthreads();
    }

#pragma unroll
    for (int m = 0; m < 2; ++m)
#pragma unroll
        for (int n = 0; n < 8; ++n)
#pragma unroll
            for (int r = 0; r < 4; ++r) {
                int srow = c * 128 + w * 32 + m * 16 + l4 * 4 + r;
                int d = n * 16 + l15;
                __hip_bfloat16 hv = __float2bfloat16(acc[m][n][r]);
                ao[(size_t)(b * S + srow) * D + h * 128 + d] = *(u16*)&hv;
            }
}

extern "C" void kernel_launch(void* const* d_in, const int* in_sizes, int n_in,
                              void* d_out, int out_size, void* d_ws, size_t ws_size,
                              hipStream_t stream)
{
    const float* hs = (const float*)d_in[0];
    const float* mask = (const float*)d_in[1];
    const int* pos = (const int*)d_in[2];
    const float* Wq = (const float*)d_in[3];
    const float* Wk = (const float*)d_in[4];
    const float* Wv = (const float*)d_in[5];
    const float* Wo = (const float*)d_in[6];
    const float* ncst = (const float*)d_in[7];
    float* out = (float*)d_out;

    char* ws = (char*)d_ws;
    size_t off = 0;
    auto alloc = [&](size_t bytes) {
        size_t o = off;
        off += (bytes + 255) & ~(size_t)255;
        return o;
    };
    u16* hs16 = (u16*)(ws + alloc((size_t)B * S * D * 2));
    u16* wqkv16 = (u16*)(ws + alloc((size_t)NQKV * D * 2));
    u16* wo16 = (u16*)(ws + alloc((size_t)D * D * 2));
    u16* tmpb = (u16*)(ws + alloc((size_t)B * S * NQKV * 2));
    u16* qn16 = (u16*)(ws + alloc((size_t)B * S * D * 2));
    u16* kn16 = (u16*)(ws + alloc((size_t)B * S * D * 2));
    u16* vT16 = (u16*)(ws + alloc((size_t)B * S * D * 2));
    float* sinb = (float*)(ws + alloc((size_t)B * S * 32 * 4));
    float* cosb = (float*)(ws + alloc((size_t)B * S * 32 * 4));
    float* keep = (float*)(ws + alloc((size_t)B * S * 4));
    float* counts = (float*)(ws + alloc((size_t)B * S * 4));
    float* expo = (float*)(ws + alloc(64));
    u16* ao16 = tmpb;
    u16* T16 = tmpb + (size_t)8388608;
    u16* P16 = tmpb + (size_t)16777216;

    cast_kernel<<<2048, 256, 0, stream>>>(hs, hs16, B * S * D / 4);
    castw_kernel<<<dim3(512, 4), 256, 0, stream>>>(
        Wq, Wk, Wv, Wo,
        wqkv16, wqkv16 + (size_t)D * D, wqkv16 + (size_t)2 * D * D, wo16, D * D / 4);
    prep_kernel<<<(B * S * 32 + 255) / 256, 256, 0, stream>>>(mask, pos, ncst, sinb, cosb, keep, expo);
    counts_kernel<<<B, 256, 0, stream>>>(keep, counts);

    // fused QKV projection (bf16 out): M=4096, N=6144, K=2048 -> 16x24=384 blocks
    gemm8p<1><<<(4096 / 256) * (NQKV / 256), 512, 0, stream>>>(
        hs16, wqkv16, nullptr, tmpb, NQKV, D, NQKV / 256);

    postproc_all<<<(B * S * H) / 4, 256, 0, stream>>>(tmpb, qn16, kn16, vT16, sinb, cosb, keep, counts, expo);

    dim3 gc(S / 128, B * H);
    chunk_state<<<gc, 256, 0, stream>>>(kn16, vT16, T16);
    prefix_state<<<256, 256, 0, stream>>>(T16, P16);
    attn2<<<gc, 256, 0, stream>>>(qn16, kn16, vT16, P16, ao16);

    // output projection -> f32 out: M=4096, N=2048, K=2048 -> 16x8=128 blocks
    gemm8p<0><<<(4096 / 256) * (D / 256), 512, 0, stream>>>(
        ao16, wo16, out, nullptr, D, D, D / 256);
}

// Round 7
// 288.145 us; speedup vs baseline: 1.0826x; 1.0826x over previous
//
#include <hip/hip_runtime.h>
#include <hip/hip_bf16.h>

typedef __attribute__((ext_vector_type(8))) short bf16x8;
typedef __attribute__((ext_vector_type(4))) float f32x4;
typedef unsigned short u16;
typedef unsigned int u32;

constexpr int B = 2, S = 2048, D = 2048, H = 16, HD = 128, ROT = 64;
constexpr int NQKV = 3 * D;  // 6144

__device__ __forceinline__ void gload16(const u16* g, u16* l)
{
    __builtin_amdgcn_global_load_lds((const __attribute__((address_space(1))) void*)g,
                                     (__attribute__((address_space(3))) void*)l, 16, 0, 0);
}

__device__ __forceinline__ float bf2f(u32 lo16) { return __uint_as_float(lo16 << 16); }

// ---------------- cast f32 -> bf16 (vectorized) ----------------
__global__ void cast_kernel(const float* __restrict__ in, u16* __restrict__ out, int n4)
{
    int idx = blockIdx.x * blockDim.x + threadIdx.x;
    int stride = gridDim.x * blockDim.x;
    for (int i = idx; i < n4; i += stride) {
        float4 v = ((const float4*)in)[i];
        __hip_bfloat16 a = __float2bfloat16(v.x);
        __hip_bfloat16 b = __float2bfloat16(v.y);
        __hip_bfloat16 c = __float2bfloat16(v.z);
        __hip_bfloat16 d = __float2bfloat16(v.w);
        ushort4 o;
        o.x = *(u16*)&a; o.y = *(u16*)&b; o.z = *(u16*)&c; o.w = *(u16*)&d;
        ((ushort4*)out)[i] = o;
    }
}

// ---------------- fused 4-weight cast ----------------
__global__ void castw_kernel(const float* __restrict__ w0, const float* __restrict__ w1,
                             const float* __restrict__ w2, const float* __restrict__ w3,
                             u16* __restrict__ o0, u16* __restrict__ o1,
                             u16* __restrict__ o2, u16* __restrict__ o3, int n4)
{
    int which = blockIdx.y;
    const float* src = which == 0 ? w0 : which == 1 ? w1 : which == 2 ? w2 : w3;
    u16* dst = which == 0 ? o0 : which == 1 ? o1 : which == 2 ? o2 : o3;
    int idx = blockIdx.x * blockDim.x + threadIdx.x;
    int stride = gridDim.x * blockDim.x;
    for (int i = idx; i < n4; i += stride) {
        float4 v = ((const float4*)src)[i];
        __hip_bfloat16 a = __float2bfloat16(v.x);
        __hip_bfloat16 b = __float2bfloat16(v.y);
        __hip_bfloat16 c = __float2bfloat16(v.z);
        __hip_bfloat16 d = __float2bfloat16(v.w);
        ushort4 o;
        o.x = *(u16*)&a; o.y = *(u16*)&b; o.z = *(u16*)&c; o.w = *(u16*)&d;
        ((ushort4*)dst)[i] = o;
    }
}

// ---------------- prep: rope tables, keep, expo ----------------
__global__ void prep_kernel(const float* __restrict__ mask, const int* __restrict__ pos,
                            const float* __restrict__ ncst,
                            float* __restrict__ sinb, float* __restrict__ cosb,
                            float* __restrict__ keep, float* __restrict__ expo)
{
    int gid = blockIdx.x * blockDim.x + threadIdx.x;
    int total = B * S * 32;
    if (gid < total) {
        int j = gid & 31;
        int bs = gid >> 5;
        float p = (float)pos[bs];
        float f = powf(10000.f, -(float)j / 32.f);
        float ang = p * f;
        sinb[gid] = sinf(ang);
        cosb[gid] = cosf(ang);
        if (j == 0) keep[bs] = (mask[bs] == 0.f) ? 1.f : 0.f;
    }
    if (gid < H) expo[gid] = 1.f / (1.f + expf(-ncst[gid]));
}

// ---------------- counts: inclusive prefix sum of keep per batch ----------------
__global__ void counts_kernel(const float* __restrict__ keep, float* __restrict__ counts)
{
    __shared__ float part[256];
    int b = blockIdx.x, t = threadIdx.x;
    float v[8];
    float s = 0.f;
    const float* kp = keep + b * S + t * 8;
#pragma unroll
    for (int i = 0; i < 8; ++i) { s += kp[i]; v[i] = s; }
    part[t] = s;
    __syncthreads();
    float off = 0.f;
    for (int j = 0; j < t; ++j) off += part[j];
    float* cp = counts + b * S + t * 8;
#pragma unroll
    for (int i = 0; i < 8; ++i) cp[i] = off + v[i];
}

// =======================================================================
// BK=32 tiled bf16 B^T GEMM, exact one-round grids (256 blocks).
// 512 thr / 8 waves (2M x 4N). Double-buffered LDS, burst prefetch 1 tile
// ahead, vmcnt(CA+CB) counted wait, 2 barriers/tile. XOR swizzle for
// 64B rows: slot ^= (row>>1)&3 on BOTH pre-swizzled source and ds_read
// (rule 21) -> 2 lanes/bank-quad = conflict-free.
// =======================================================================

template <int CNT>
__device__ __forceinline__ void stage_op(const u16* __restrict__ G, int K,
                                         int trow0, int kt, u16* lbuf, int tid)
{
#pragma unroll
    for (int l = 0; l < CNT; ++l) {
        int idx = l * 512 + tid;
        int row = idx >> 2;
        int slot = idx & 3;
        int col8 = slot ^ ((row >> 1) & 3);  // inverse-swizzled source
        const u16* g = G + (size_t)(trow0 + row) * K + kt * 32 + col8 * 8;
        u16* ld = lbuf + (size_t)(idx & ~63) * 8;  // wave-uniform base + lane*16B
        gload16(g, ld);
    }
}

template <int BM, int BN, int CA, int CB, int MR, int NR, int BF16OUT>
__global__ __launch_bounds__(512, 2) void gemm32(
    const u16* __restrict__ A, const u16* __restrict__ Bm,
    float* __restrict__ Cf, u16* __restrict__ Cb, int N, int K, int ntn)
{
    __shared__ u16 As[2 * BM * 32];
    __shared__ u16 Bs[2 * BN * 32];
    const int tid = threadIdx.x;
    const int lane = tid & 63;
    const int w = tid >> 6;     // 0..7
    const int wm = w >> 2;      // 0..1
    const int wn = w & 3;       // 0..3
    const int l15 = lane & 15, l4 = lane >> 4;

    // bijective XCD-aware swizzle: nwg=256 -> 32 consecutive tiles per XCD
    int nwg = gridDim.x;
    int bid = blockIdx.x;
    int cpx = nwg >> 3;
    int sbid = (bid & 7) * cpx + (bid >> 3);
    int bm = sbid / ntn, bn = sbid % ntn;
    const int bmrow = bm * BM, bnrow = bn * BN;

    f32x4 acc[MR][NR] = {};
    const int nk = K >> 5;

    // prologue: stage tile 0 into buf 0
    stage_op<CA>(A, K, bmrow, 0, &As[0], tid);
    stage_op<CB>(Bm, K, bnrow, 0, &Bs[0], tid);

    for (int t = 0; t < nk; ++t) {
        const u16* ab = &As[(t & 1) * BM * 32];
        const u16* bb = &Bs[(t & 1) * BN * 32];
        if (t + 1 < nk) {
            // stage t+1 into buf^1 (its last readers finished before the
            // end-of-tile barrier of t-1, already passed by all waves)
            stage_op<CA>(A, K, bmrow, t + 1, &As[((t + 1) & 1) * BM * 32], tid);
            stage_op<CB>(Bm, K, bnrow, t + 1, &Bs[((t + 1) & 1) * BN * 32], tid);
            // 2(CA+CB) outstanding; certify oldest CA+CB (= tile t)
            asm volatile("s_waitcnt vmcnt(%0)" :: "i"(CA + CB) : "memory");
        } else {
            asm volatile("s_waitcnt vmcnt(0)" ::: "memory");
        }
        __builtin_amdgcn_sched_barrier(0);
        __builtin_amdgcn_s_barrier();  // all waves certified tile t resident

        bf16x8 af[MR];
#pragma unroll
        for (int i = 0; i < MR; ++i) {
            int row = wm * (BM / 2) + i * 16 + l15;
            int slot = l4 ^ ((row >> 1) & 3);
            af[i] = *(const bf16x8*)(ab + row * 32 + slot * 8);
        }
#pragma unroll
        for (int n = 0; n < NR; ++n) {
            int brow = wn * (BN / 4) + n * 16 + l15;
            int bslot = l4 ^ ((brow >> 1) & 3);
            bf16x8 bf = *(const bf16x8*)(bb + brow * 32 + bslot * 8);
            __builtin_amdgcn_s_setprio(1);
#pragma unroll
            for (int i = 0; i < MR; ++i)
                acc[i][n] = __builtin_amdgcn_mfma_f32_16x16x32_bf16(af[i], bf, acc[i][n], 0, 0, 0);
            __builtin_amdgcn_s_setprio(0);
        }
        __builtin_amdgcn_sched_barrier(0);
        __builtin_amdgcn_s_barrier();  // all reads done before next-iter stages
    }

    // epilogue
#pragma unroll
    for (int i = 0; i < MR; ++i) {
        int row = bmrow + wm * (BM / 2) + i * 16 + l4 * 4;
#pragma unroll
        for (int n = 0; n < NR; ++n) {
            int col = bnrow + wn * (BN / 4) + n * 16 + l15;
            f32x4 v = acc[i][n];
#pragma unroll
            for (int r = 0; r < 4; ++r) {
                if (BF16OUT) {
                    __hip_bfloat16 hv = __float2bfloat16(v[r]);
                    Cb[(size_t)(row + r) * N + col] = *(u16*)&hv;
                } else {
                    Cf[(size_t)(row + r) * N + col] = v[r];
                }
            }
        }
    }
}

// ---------------- fused postproc: RoPE + norm (q,k), count-scale (v) ----------------
__global__ void postproc_all(const u16* __restrict__ tmpb,
                             u16* __restrict__ qn, u16* __restrict__ kn, u16* __restrict__ vT,
                             const float* __restrict__ sinb, const float* __restrict__ cosb,
                             const float* __restrict__ keep, const float* __restrict__ counts,
                             const float* __restrict__ expo)
{
    int gw = (blockIdx.x * blockDim.x + threadIdx.x) >> 6;
    int lane = threadIdx.x & 63;
    if (gw >= B * S * H) return;
    int h = gw % H;
    int sb = gw / H;
    int s = sb % S;
    int b = sb / S;
    const u16* rowp = tmpb + (size_t)(b * S + s) * NQKV;
    u32 qv = *(const u32*)(rowp + h * 128 + lane * 2);
    u32 kv = *(const u32*)(rowp + D + h * 128 + lane * 2);
    u32 vv = *(const u32*)(rowp + 2 * D + h * 128 + lane * 2);
    float q0 = bf2f(qv & 0xffff), q1 = bf2f(qv >> 16);
    float k0 = bf2f(kv & 0xffff), k1 = bf2f(kv >> 16);
    float v0 = bf2f(vv & 0xffff), v1 = bf2f(vv >> 16);
    if (lane < 32) {
        float sn = sinb[(b * S + s) * 32 + lane];
        float cs = cosb[(b * S + s) * 32 + lane];
        float nq0 = q0 * cs - q1 * sn, nq1 = q1 * cs + q0 * sn;
        float nk0 = k0 * cs - k1 * sn, nk1 = k1 * cs + k0 * sn;
        q0 = nq0; q1 = nq1; k0 = nk0; k1 = nk1;
    }
    float sq = q0 * q0 + q1 * q1;
    float sk = k0 * k0 + k1 * k1;
#pragma unroll
    for (int o = 1; o < 64; o <<= 1) {
        sq += __shfl_xor(sq, o, 64);
        sk += __shfl_xor(sk, o, 64);
    }
    float kf = keep[b * S + s];
    float scq = kf / fmaxf(sqrtf(sq), 1e-12f);
    float sck = kf / fmaxf(sqrtf(sk), 1e-12f);
    float cnt = counts[b * S + s];
    float e = expo[h];
    float scv = kf / fmaxf(powf(cnt, e), 1.0f);

    __hip_bfloat16 a0 = __float2bfloat16(q0 * scq), a1 = __float2bfloat16(q1 * scq);
    __hip_bfloat16 b0 = __float2bfloat16(k0 * sck), b1 = __float2bfloat16(k1 * sck);
    __hip_bfloat16 c0 = __float2bfloat16(v0 * scv), c1 = __float2bfloat16(v1 * scv);
    size_t obase = ((size_t)(b * H + h) * S + s) * 128 + lane * 2;
    *(u32*)(qn + obase) = (u32)*(u16*)&a0 | ((u32)*(u16*)&a1 << 16);
    *(u32*)(kn + obase) = (u32)*(u16*)&b0 | ((u32)*(u16*)&b1 << 16);
    size_t vbase = ((size_t)(b * H + h) * 128) * (size_t)S + s;
    vT[vbase + (size_t)(2 * lane) * S] = *(u16*)&c0;
    vT[vbase + (size_t)(2 * lane + 1) * S] = *(u16*)&c1;
}

// ---------------- chunk state: T_c[d][d'] = sum_{k in chunk} v[k,d] * kn[k,d'] ----------------
__global__ __launch_bounds__(256) void chunk_state(
    const u16* __restrict__ kn, const u16* __restrict__ vT, u16* __restrict__ T16)
{
    __shared__ u16 As[128][72];
    __shared__ u16 Bs[128][72];
    int tid = threadIdx.x, lane = tid & 63, w = tid >> 6;
    int wm = w >> 1, wn = w & 1;
    int c = blockIdx.x, bh = blockIdx.y;
    const int l15 = lane & 15, l4 = lane >> 4;
    size_t vbase = (size_t)bh * 128 * S;
    size_t kbase = (size_t)bh * S * 128;
    f32x4 acc[4][4] = {};

    for (int t = 0; t < 2; ++t) {
#pragma unroll
        for (int i = 0; i < 4; ++i) {
            int q = tid + i * 256;
            int r = q >> 3, c8 = q & 7;
            uint4 v = *(const uint4*)(vT + vbase + (size_t)r * S + c * 128 + t * 64 + c8 * 8);
            *(uint4*)(&As[r][c8 * 8]) = v;
        }
#pragma unroll
        for (int i = 0; i < 4; ++i) {
            int q = tid + i * 256;
            int r = q >> 4, c16 = q & 15;
            uint4 v = *(const uint4*)(kn + kbase + (size_t)(c * 128 + t * 64 + r) * 128 + c16 * 8);
            const u16* pv = (const u16*)&v;
#pragma unroll
            for (int j = 0; j < 8; ++j) Bs[c16 * 8 + j][r] = pv[j];
        }
        __syncthreads();
#pragma unroll
        for (int tt = 0; tt < 2; ++tt) {
            bf16x8 a[4], b[4];
#pragma unroll
            for (int m = 0; m < 4; ++m)
                a[m] = *(const bf16x8*)(&As[wm * 64 + m * 16 + l15][tt * 32 + l4 * 8]);
#pragma unroll
            for (int n = 0; n < 4; ++n)
                b[n] = *(const bf16x8*)(&Bs[wn * 64 + n * 16 + l15][tt * 32 + l4 * 8]);
#pragma unroll
            for (int m = 0; m < 4; ++m)
#pragma unroll
                for (int n = 0; n < 4; ++n)
                    acc[m][n] = __builtin_amdgcn_mfma_f32_16x16x32_bf16(a[m], b[n], acc[m][n], 0, 0, 0);
        }
        __syncthreads();
    }
#pragma unroll
    for (int m = 0; m < 4; ++m) {
        int row = wm * 64 + m * 16 + l4 * 4;
#pragma unroll
        for (int n = 0; n < 4; ++n) {
            int col = wn * 64 + n * 16 + l15;
#pragma unroll
            for (int r = 0; r < 4; ++r) {
                __hip_bfloat16 hv = __float2bfloat16(acc[m][n][r]);
                T16[((size_t)(bh * 16 + c) * 128 + row + r) * 128 + col] = *(u16*)&hv;
            }
        }
    }
}

// ---------------- exclusive prefix over chunks: P_c = sum_{c'<c} T_c' ----------------
__global__ void prefix_state(const u16* __restrict__ T16, u16* __restrict__ P16)
{
    int g = blockIdx.x * blockDim.x + threadIdx.x;
    int bh = g >> 11;
    int i8 = (g & 2047) * 8;
    const u16* tp = T16 + (size_t)bh * 16 * 16384 + i8;
    u16* pp = P16 + (size_t)bh * 16 * 16384 + i8;
    float run[8] = {};
    for (int c = 0; c < 16; ++c) {
        u16 ob[8];
#pragma unroll
        for (int j = 0; j < 8; ++j) { __hip_bfloat16 hv = __float2bfloat16(run[j]); ob[j] = *(u16*)&hv; }
        *(uint4*)(pp + (size_t)c * 16384) = *(uint4*)ob;
        uint4 tv = *(const uint4*)(tp + (size_t)c * 16384);
        const u16* tvp = (const u16*)&tv;
#pragma unroll
        for (int j = 0; j < 8; ++j) run[j] += bf2f(tvp[j]);
    }
}

// ---------------- chunked attention: out_c = qn_c . P_c + causal_intra ----------------
__global__ __launch_bounds__(256, 2) void attn2(
    const u16* __restrict__ qn, const u16* __restrict__ kn,
    const u16* __restrict__ vT, const u16* __restrict__ P16, u16* __restrict__ ao)
{
    __shared__ u16 KN[64][136];
    __shared__ u16 VT[128][72];
    __shared__ u16 SC[128][72];
    int tid = threadIdx.x, lane = tid & 63, w = tid >> 6;
    int c = blockIdx.x, bh = blockIdx.y;
    int b = bh >> 4, h = bh & 15;
    const int l15 = lane & 15, l4 = lane >> 4;
    size_t base = (size_t)bh * S * 128;
    size_t vbase = (size_t)bh * 128 * S;
    const u16* Pp = P16 + (size_t)(bh * 16 + c) * 16384;

    bf16x8 qa[2][4];
#pragma unroll
    for (int m = 0; m < 2; ++m)
#pragma unroll
        for (int t = 0; t < 4; ++t) {
            int row = c * 128 + w * 32 + m * 16 + l15;
            qa[m][t] = *(const bf16x8*)(qn + base + (size_t)row * 128 + t * 32 + l4 * 8);
        }

    f32x4 acc[2][8] = {};

#pragma unroll
    for (int pt = 0; pt < 2; ++pt) {
#pragma unroll
        for (int i = 0; i < 4; ++i) {
            int q = tid + i * 256;
            int r = q >> 3, c8 = q & 7;
            uint4 v = *(const uint4*)(Pp + (size_t)r * 128 + pt * 64 + c8 * 8);
            *(uint4*)(&VT[r][c8 * 8]) = v;
        }
        __syncthreads();
#pragma unroll
        for (int tt = 0; tt < 2; ++tt) {
            bf16x8 pb[8];
#pragma unroll
            for (int n = 0; n < 8; ++n)
                pb[n] = *(const bf16x8*)(&VT[n * 16 + l15][tt * 32 + l4 * 8]);
#pragma unroll
            for (int m = 0; m < 2; ++m)
#pragma unroll
                for (int n = 0; n < 8; ++n)
                    acc[m][n] = __builtin_amdgcn_mfma_f32_16x16x32_bf16(qa[m][pt * 2 + tt], pb[n], acc[m][n], 0, 0, 0);
        }
        __syncthreads();
    }

    for (int kt2 = 0; kt2 < 2; ++kt2) {
#pragma unroll
        for (int i = 0; i < 4; ++i) {
            int q = tid + i * 256;
            int r = q >> 4, c8 = q & 15;
            uint4 v = *(const uint4*)(kn + base + (size_t)(c * 128 + kt2 * 64 + r) * 128 + c8 * 8);
            *(uint4*)(&KN[r][c8 * 8]) = v;
        }
#pragma unroll
        for (int i = 0; i < 4; ++i) {
            int q = tid + i * 256;
            int r = q >> 3, c8 = q & 7;
            uint4 v = *(const uint4*)(vT + vbase + (size_t)r * S + c * 128 + kt2 * 64 + c8 * 8);
            *(uint4*)(&VT[r][c8 * 8]) = v;
        }
        __syncthreads();
        f32x4 sacc[2][4] = {};
#pragma unroll
        for (int t = 0; t < 4; ++t) {
            bf16x8 kb[4];
#pragma unroll
            for (int n = 0; n < 4; ++n)
                kb[n] = *(const bf16x8*)(&KN[n * 16 + l15][t * 32 + l4 * 8]);
#pragma unroll
            for (int m = 0; m < 2; ++m)
#pragma unroll
                for (int n = 0; n < 4; ++n)
                    sacc[m][n] = __builtin_amdgcn_mfma_f32_16x16x32_bf16(qa[m][t], kb[n], sacc[m][n], 0, 0, 0);
        }
#pragma unroll
        for (int m = 0; m < 2; ++m)
#pragma unroll
            for (int n = 0; n < 4; ++n)
#pragma unroll
                for (int r = 0; r < 4; ++r) {
                    int rowl = w * 32 + m * 16 + l4 * 4 + r;
                    int coll = n * 16 + l15;
                    int kl = kt2 * 64 + coll;
                    float val = (kl <= rowl) ? sacc[m][n][r] : 0.f;
                    __hip_bfloat16 hv = __float2bfloat16(val);
                    SC[rowl][coll] = *(u16*)&hv;
                }
#pragma unroll
        for (int t = 0; t < 2; ++t) {
            bf16x8 sa[2], vb[8];
#pragma unroll
            for (int m = 0; m < 2; ++m)
                sa[m] = *(const bf16x8*)(&SC[w * 32 + m * 16 + l15][t * 32 + l4 * 8]);
#pragma unroll
            for (int n = 0; n < 8; ++n)
                vb[n] = *(const bf16x8*)(&VT[n * 16 + l15][t * 32 + l4 * 8]);
#pragma unroll
            for (int m = 0; m < 2; ++m)
#pragma unroll
                for (int n = 0; n < 8; ++n)
                    acc[m][n] = __builtin_amdgcn_mfma_f32_16x16x32_bf16(sa[m], vb[n], acc[m][n], 0, 0, 0);
        }
        __syncthreads();
    }

#pragma unroll
    for (int m = 0; m < 2; ++m)
#pragma unroll
        for (int n = 0; n < 8; ++n)
#pragma unroll
            for (int r = 0; r < 4; ++r) {
                int srow = c * 128 + w * 32 + m * 16 + l4 * 4 + r;
                int d = n * 16 + l15;
                __hip_bfloat16 hv = __float2bfloat16(acc[m][n][r]);
                ao[(size_t)(b * S + srow) * D + h * 128 + d] = *(u16*)&hv;
            }
}

extern "C" void kernel_launch(void* const* d_in, const int* in_sizes, int n_in,
                              void* d_out, int out_size, void* d_ws, size_t ws_size,
                              hipStream_t stream)
{
    const float* hs = (const float*)d_in[0];
    const float* mask = (const float*)d_in[1];
    const int* pos = (const int*)d_in[2];
    const float* Wq = (const float*)d_in[3];
    const float* Wk = (const float*)d_in[4];
    const float* Wv = (const float*)d_in[5];
    const float* Wo = (const float*)d_in[6];
    const float* ncst = (const float*)d_in[7];
    float* out = (float*)d_out;

    char* ws = (char*)d_ws;
    size_t off = 0;
    auto alloc = [&](size_t bytes) {
        size_t o = off;
        off += (bytes + 255) & ~(size_t)255;
        return o;
    };
    u16* hs16 = (u16*)(ws + alloc((size_t)B * S * D * 2));
    u16* wqkv16 = (u16*)(ws + alloc((size_t)NQKV * D * 2));
    u16* wo16 = (u16*)(ws + alloc((size_t)D * D * 2));
    u16* tmpb = (u16*)(ws + alloc((size_t)B * S * NQKV * 2));
    u16* qn16 = (u16*)(ws + alloc((size_t)B * S * D * 2));
    u16* kn16 = (u16*)(ws + alloc((size_t)B * S * D * 2));
    u16* vT16 = (u16*)(ws + alloc((size_t)B * S * D * 2));
    float* sinb = (float*)(ws + alloc((size_t)B * S * 32 * 4));
    float* cosb = (float*)(ws + alloc((size_t)B * S * 32 * 4));
    float* keep = (float*)(ws + alloc((size_t)B * S * 4));
    float* counts = (float*)(ws + alloc((size_t)B * S * 4));
    float* expo = (float*)(ws + alloc(64));
    u16* ao16 = tmpb;
    u16* T16 = tmpb + (size_t)8388608;
    u16* P16 = tmpb + (size_t)16777216;

    cast_kernel<<<2048, 256, 0, stream>>>(hs, hs16, B * S * D / 4);
    castw_kernel<<<dim3(512, 4), 256, 0, stream>>>(
        Wq, Wk, Wv, Wo,
        wqkv16, wqkv16 + (size_t)D * D, wqkv16 + (size_t)2 * D * D, wo16, D * D / 4);
    prep_kernel<<<(B * S * 32 + 255) / 256, 256, 0, stream>>>(mask, pos, ncst, sinb, cosb, keep, expo);
    counts_kernel<<<B, 256, 0, stream>>>(keep, counts);

    // fused QKV projection (bf16 out): 256x384 tiles -> 16x16 = 256 blocks (1 round)
    gemm32<256, 384, 2, 3, 8, 6, 1><<<256, 512, 0, stream>>>(
        hs16, wqkv16, nullptr, tmpb, NQKV, D, NQKV / 384);

    postproc_all<<<(B * S * H) / 4, 256, 0, stream>>>(tmpb, qn16, kn16, vT16, sinb, cosb, keep, counts, expo);

    dim3 gc(S / 128, B * H);
    chunk_state<<<gc, 256, 0, stream>>>(kn16, vT16, T16);
    prefix_state<<<256, 256, 0, stream>>>(T16, P16);
    attn2<<<gc, 256, 0, stream>>>(qn16, kn16, vT16, P16, ao16);

    // output projection -> f32 out: 128x256 tiles -> 32x8 = 256 blocks (1 round)
    gemm32<128, 256, 1, 2, 4, 4, 0><<<256, 512, 0, stream>>>(
        ao16, wo16, out, nullptr, D, D, D / 256);
}

// Round 8
// 282.756 us; speedup vs baseline: 1.1032x; 1.0191x over previous
//
#include <hip/hip_runtime.h>
#include <hip/hip_bf16.h>

typedef __attribute__((ext_vector_type(8))) short bf16x8;
typedef __attribute__((ext_vector_type(4))) float f32x4;
typedef unsigned short u16;
typedef unsigned int u32;

constexpr int B = 2, S = 2048, D = 2048, H = 16, HD = 128, ROT = 64;
constexpr int NQKV = 3 * D;  // 6144

__device__ __forceinline__ void gload16(const u16* g, u16* l)
{
    __builtin_amdgcn_global_load_lds((const __attribute__((address_space(1))) void*)g,
                                     (__attribute__((address_space(3))) void*)l, 16, 0, 0);
}

__device__ __forceinline__ float bf2f(u32 lo16) { return __uint_as_float(lo16 << 16); }

// ---------------- cast f32 -> bf16 (vectorized) ----------------
__global__ void cast_kernel(const float* __restrict__ in, u16* __restrict__ out, int n4)
{
    int idx = blockIdx.x * blockDim.x + threadIdx.x;
    int stride = gridDim.x * blockDim.x;
    for (int i = idx; i < n4; i += stride) {
        float4 v = ((const float4*)in)[i];
        __hip_bfloat16 a = __float2bfloat16(v.x);
        __hip_bfloat16 b = __float2bfloat16(v.y);
        __hip_bfloat16 c = __float2bfloat16(v.z);
        __hip_bfloat16 d = __float2bfloat16(v.w);
        ushort4 o;
        o.x = *(u16*)&a; o.y = *(u16*)&b; o.z = *(u16*)&c; o.w = *(u16*)&d;
        ((ushort4*)out)[i] = o;
    }
}

// ---------------- fused 4-weight cast ----------------
__global__ void castw_kernel(const float* __restrict__ w0, const float* __restrict__ w1,
                             const float* __restrict__ w2, const float* __restrict__ w3,
                             u16* __restrict__ o0, u16* __restrict__ o1,
                             u16* __restrict__ o2, u16* __restrict__ o3, int n4)
{
    int which = blockIdx.y;
    const float* src = which == 0 ? w0 : which == 1 ? w1 : which == 2 ? w2 : w3;
    u16* dst = which == 0 ? o0 : which == 1 ? o1 : which == 2 ? o2 : o3;
    int idx = blockIdx.x * blockDim.x + threadIdx.x;
    int stride = gridDim.x * blockDim.x;
    for (int i = idx; i < n4; i += stride) {
        float4 v = ((const float4*)src)[i];
        __hip_bfloat16 a = __float2bfloat16(v.x);
        __hip_bfloat16 b = __float2bfloat16(v.y);
        __hip_bfloat16 c = __float2bfloat16(v.z);
        __hip_bfloat16 d = __float2bfloat16(v.w);
        ushort4 o;
        o.x = *(u16*)&a; o.y = *(u16*)&b; o.z = *(u16*)&c; o.w = *(u16*)&d;
        ((ushort4*)dst)[i] = o;
    }
}

// ---------------- prep: rope tables, keep, expo ----------------
__global__ void prep_kernel(const float* __restrict__ mask, const int* __restrict__ pos,
                            const float* __restrict__ ncst,
                            float* __restrict__ sinb, float* __restrict__ cosb,
                            float* __restrict__ keep, float* __restrict__ expo)
{
    int gid = blockIdx.x * blockDim.x + threadIdx.x;
    int total = B * S * 32;
    if (gid < total) {
        int j = gid & 31;
        int bs = gid >> 5;
        float p = (float)pos[bs];
        float f = powf(10000.f, -(float)j / 32.f);
        float ang = p * f;
        sinb[gid] = sinf(ang);
        cosb[gid] = cosf(ang);
        if (j == 0) keep[bs] = (mask[bs] == 0.f) ? 1.f : 0.f;
    }
    if (gid < H) expo[gid] = 1.f / (1.f + expf(-ncst[gid]));
}

// ---------------- counts: inclusive prefix sum of keep per batch ----------------
__global__ void counts_kernel(const float* __restrict__ keep, float* __restrict__ counts)
{
    __shared__ float part[256];
    int b = blockIdx.x, t = threadIdx.x;
    float v[8];
    float s = 0.f;
    const float* kp = keep + b * S + t * 8;
#pragma unroll
    for (int i = 0; i < 8; ++i) { s += kp[i]; v[i] = s; }
    part[t] = s;
    __syncthreads();
    float off = 0.f;
    for (int j = 0; j < t; ++j) off += part[j];
    float* cp = counts + b * S + t * 8;
#pragma unroll
    for (int i = 0; i < 8; ++i) cp[i] = off + v[i];
}

// =======================================================================
// BK=32 tiled bf16 B^T GEMM, exact one-round grids (256 blocks),
// TRIPLE-buffered LDS with prefetch distance 2: at tile t stage t+2,
// vmcnt(2*(CA+CB)) certifies tile t whose loads got 2 full iterations of
// cover. 2 barriers/tile. XOR swizzle (slot ^= (row>>1)&3) on both
// pre-swizzled source and ds_read (rule 21) -> 2 lanes/bank-quad = free.
// =======================================================================

template <int CNT>
__device__ __forceinline__ void stage_op(const u16* __restrict__ G, int K,
                                         int trow0, int kt, u16* lbuf, int tid)
{
#pragma unroll
    for (int l = 0; l < CNT; ++l) {
        int idx = l * 512 + tid;
        int row = idx >> 2;
        int slot = idx & 3;
        int col8 = slot ^ ((row >> 1) & 3);  // inverse-swizzled source
        const u16* g = G + (size_t)(trow0 + row) * K + kt * 32 + col8 * 8;
        u16* ld = lbuf + (size_t)(idx & ~63) * 8;  // wave-uniform base + lane*16B
        gload16(g, ld);
    }
}

template <int BM, int BN, int CA, int CB, int MR, int NR, int BF16OUT>
__global__ __launch_bounds__(512, 2) void gemm32(
    const u16* __restrict__ A, const u16* __restrict__ Bm,
    float* __restrict__ Cf, u16* __restrict__ Cb, int N, int K, int ntn)
{
    __shared__ u16 As[3 * BM * 32];
    __shared__ u16 Bs[3 * BN * 32];
    const int tid = threadIdx.x;
    const int lane = tid & 63;
    const int w = tid >> 6;     // 0..7
    const int wm = w >> 2;      // 0..1
    const int wn = w & 3;       // 0..3
    const int l15 = lane & 15, l4 = lane >> 4;

    // bijective XCD-aware swizzle: nwg=256 -> 32 consecutive tiles per XCD
    int nwg = gridDim.x;
    int bid = blockIdx.x;
    int cpx = nwg >> 3;
    int sbid = (bid & 7) * cpx + (bid >> 3);
    int bm = sbid / ntn, bn = sbid % ntn;
    const int bmrow = bm * BM, bnrow = bn * BN;

    f32x4 acc[MR][NR] = {};
    const int nk = K >> 5;

    // prologue: stage tile 0 -> buf0, tile 1 -> buf1
    stage_op<CA>(A, K, bmrow, 0, &As[0], tid);
    stage_op<CB>(Bm, K, bnrow, 0, &Bs[0], tid);
    stage_op<CA>(A, K, bmrow, 1, &As[BM * 32], tid);
    stage_op<CB>(Bm, K, bnrow, 1, &Bs[BN * 32], tid);

    int c0 = 0;  // buffer index of tile t
    for (int t = 0; t < nk; ++t) {
        const u16* ab = &As[c0 * BM * 32];
        const u16* bb = &Bs[c0 * BN * 32];
        if (t + 2 < nk) {
            int c2 = c0 + 2; if (c2 >= 3) c2 -= 3;
            // buf c2's last readers were tile t-1 (finished before the
            // closing barrier of t-1, which all waves already passed)
            stage_op<CA>(A, K, bmrow, t + 2, &As[c2 * BM * 32], tid);
            stage_op<CB>(Bm, K, bnrow, t + 2, &Bs[c2 * BN * 32], tid);
            // outstanding = tiles t+1, t+2 -> certify tile t
            asm volatile("s_waitcnt vmcnt(%0)" :: "i"(2 * (CA + CB)) : "memory");
        } else if (t + 1 < nk) {
            asm volatile("s_waitcnt vmcnt(%0)" :: "i"(CA + CB) : "memory");
        } else {
            asm volatile("s_waitcnt vmcnt(0)" ::: "memory");
        }
        __builtin_amdgcn_sched_barrier(0);
        __builtin_amdgcn_s_barrier();  // all waves certified tile t resident

        bf16x8 af[MR];
#pragma unroll
        for (int i = 0; i < MR; ++i) {
            int row = wm * (BM / 2) + i * 16 + l15;
            int slot = l4 ^ ((row >> 1) & 3);
            af[i] = *(const bf16x8*)(ab + row * 32 + slot * 8);
        }
#pragma unroll
        for (int n = 0; n < NR; ++n) {
            int brow = wn * (BN / 4) + n * 16 + l15;
            int bslot = l4 ^ ((brow >> 1) & 3);
            bf16x8 bf = *(const bf16x8*)(bb + brow * 32 + bslot * 8);
            __builtin_amdgcn_s_setprio(1);
#pragma unroll
            for (int i = 0; i < MR; ++i)
                acc[i][n] = __builtin_amdgcn_mfma_f32_16x16x32_bf16(af[i], bf, acc[i][n], 0, 0, 0);
            __builtin_amdgcn_s_setprio(0);
        }
        __builtin_amdgcn_sched_barrier(0);
        __builtin_amdgcn_s_barrier();  // all reads done before next-iter stages
        c0 = (c0 + 1 == 3) ? 0 : c0 + 1;
    }

    // epilogue
#pragma unroll
    for (int i = 0; i < MR; ++i) {
        int row = bmrow + wm * (BM / 2) + i * 16 + l4 * 4;
#pragma unroll
        for (int n = 0; n < NR; ++n) {
            int col = bnrow + wn * (BN / 4) + n * 16 + l15;
            f32x4 v = acc[i][n];
#pragma unroll
            for (int r = 0; r < 4; ++r) {
                if (BF16OUT) {
                    __hip_bfloat16 hv = __float2bfloat16(v[r]);
                    Cb[(size_t)(row + r) * N + col] = *(u16*)&hv;
                } else {
                    Cf[(size_t)(row + r) * N + col] = v[r];
                }
            }
        }
    }
}

// ---------------- fused postproc: RoPE + norm (q,k), count-scale (v) ----------------
// v now written ROW-MAJOR (B,H,S,HD) with coalesced u32 stores.
__global__ void postproc_all(const u16* __restrict__ tmpb,
                             u16* __restrict__ qn, u16* __restrict__ kn, u16* __restrict__ vr,
                             const float* __restrict__ sinb, const float* __restrict__ cosb,
                             const float* __restrict__ keep, const float* __restrict__ counts,
                             const float* __restrict__ expo)
{
    int gw = (blockIdx.x * blockDim.x + threadIdx.x) >> 6;
    int lane = threadIdx.x & 63;
    if (gw >= B * S * H) return;
    int h = gw % H;
    int sb = gw / H;
    int s = sb % S;
    int b = sb / S;
    const u16* rowp = tmpb + (size_t)(b * S + s) * NQKV;
    u32 qv = *(const u32*)(rowp + h * 128 + lane * 2);
    u32 kv = *(const u32*)(rowp + D + h * 128 + lane * 2);
    u32 vv = *(const u32*)(rowp + 2 * D + h * 128 + lane * 2);
    float q0 = bf2f(qv & 0xffff), q1 = bf2f(qv >> 16);
    float k0 = bf2f(kv & 0xffff), k1 = bf2f(kv >> 16);
    float v0 = bf2f(vv & 0xffff), v1 = bf2f(vv >> 16);
    if (lane < 32) {
        float sn = sinb[(b * S + s) * 32 + lane];
        float cs = cosb[(b * S + s) * 32 + lane];
        float nq0 = q0 * cs - q1 * sn, nq1 = q1 * cs + q0 * sn;
        float nk0 = k0 * cs - k1 * sn, nk1 = k1 * cs + k0 * sn;
        q0 = nq0; q1 = nq1; k0 = nk0; k1 = nk1;
    }
    float sq = q0 * q0 + q1 * q1;
    float sk = k0 * k0 + k1 * k1;
#pragma unroll
    for (int o = 1; o < 64; o <<= 1) {
        sq += __shfl_xor(sq, o, 64);
        sk += __shfl_xor(sk, o, 64);
    }
    float kf = keep[b * S + s];
    float scq = kf / fmaxf(sqrtf(sq), 1e-12f);
    float sck = kf / fmaxf(sqrtf(sk), 1e-12f);
    float cnt = counts[b * S + s];
    float e = expo[h];
    float scv = kf / fmaxf(powf(cnt, e), 1.0f);

    __hip_bfloat16 a0 = __float2bfloat16(q0 * scq), a1 = __float2bfloat16(q1 * scq);
    __hip_bfloat16 b0 = __float2bfloat16(k0 * sck), b1 = __float2bfloat16(k1 * sck);
    __hip_bfloat16 c0 = __float2bfloat16(v0 * scv), c1 = __float2bfloat16(v1 * scv);
    size_t obase = ((size_t)(b * H + h) * S + s) * 128 + lane * 2;
    *(u32*)(qn + obase) = (u32)*(u16*)&a0 | ((u32)*(u16*)&a1 << 16);
    *(u32*)(kn + obase) = (u32)*(u16*)&b0 | ((u32)*(u16*)&b1 << 16);
    *(u32*)(vr + obase) = (u32)*(u16*)&c0 | ((u32)*(u16*)&c1 << 16);
}

// ---------------- chunk state: T_c[d][d'] = sum_{k in chunk} v[k,d] * kn[k,d'] ----------------
// v is row-major (B,H,S,HD); transpose during LDS staging (same as kn).
__global__ __launch_bounds__(256) void chunk_state(
    const u16* __restrict__ kn, const u16* __restrict__ vr, u16* __restrict__ T16)
{
    __shared__ u16 As[128][72];
    __shared__ u16 Bs[128][72];
    int tid = threadIdx.x, lane = tid & 63, w = tid >> 6;
    int wm = w >> 1, wn = w & 1;
    int c = blockIdx.x, bh = blockIdx.y;
    const int l15 = lane & 15, l4 = lane >> 4;
    size_t base = (size_t)bh * S * 128;
    f32x4 acc[4][4] = {};

    for (int t = 0; t < 2; ++t) {
        // As[d][k] <- v rows (transpose): 64 k-rows x 128 d
#pragma unroll
        for (int i = 0; i < 4; ++i) {
            int q = tid + i * 256;
            int r = q >> 4, c16 = q & 15;
            uint4 v = *(const uint4*)(vr + base + (size_t)(c * 128 + t * 64 + r) * 128 + c16 * 8);
            const u16* pv = (const u16*)&v;
#pragma unroll
            for (int j = 0; j < 8; ++j) As[c16 * 8 + j][r] = pv[j];
        }
        // Bs[d'][k] <- kn rows (transpose)
#pragma unroll
        for (int i = 0; i < 4; ++i) {
            int q = tid + i * 256;
            int r = q >> 4, c16 = q & 15;
            uint4 v = *(const uint4*)(kn + base + (size_t)(c * 128 + t * 64 + r) * 128 + c16 * 8);
            const u16* pv = (const u16*)&v;
#pragma unroll
            for (int j = 0; j < 8; ++j) Bs[c16 * 8 + j][r] = pv[j];
        }
        __syncthreads();
#pragma unroll
        for (int tt = 0; tt < 2; ++tt) {
            bf16x8 a[4], b[4];
#pragma unroll
            for (int m = 0; m < 4; ++m)
                a[m] = *(const bf16x8*)(&As[wm * 64 + m * 16 + l15][tt * 32 + l4 * 8]);
#pragma unroll
            for (int n = 0; n < 4; ++n)
                b[n] = *(const bf16x8*)(&Bs[wn * 64 + n * 16 + l15][tt * 32 + l4 * 8]);
#pragma unroll
            for (int m = 0; m < 4; ++m)
#pragma unroll
                for (int n = 0; n < 4; ++n)
                    acc[m][n] = __builtin_amdgcn_mfma_f32_16x16x32_bf16(a[m], b[n], acc[m][n], 0, 0, 0);
        }
        __syncthreads();
    }
#pragma unroll
    for (int m = 0; m < 4; ++m) {
        int row = wm * 64 + m * 16 + l4 * 4;
#pragma unroll
        for (int n = 0; n < 4; ++n) {
            int col = wn * 64 + n * 16 + l15;
#pragma unroll
            for (int r = 0; r < 4; ++r) {
                __hip_bfloat16 hv = __float2bfloat16(acc[m][n][r]);
                T16[((size_t)(bh * 16 + c) * 128 + row + r) * 128 + col] = *(u16*)&hv;
            }
        }
    }
}

// ---------------- exclusive prefix over chunks: P_c = sum_{c'<c} T_c' ----------------
__global__ void prefix_state(const u16* __restrict__ T16, u16* __restrict__ P16)
{
    int g = blockIdx.x * blockDim.x + threadIdx.x;
    int bh = g >> 11;
    int i8 = (g & 2047) * 8;
    const u16* tp = T16 + (size_t)bh * 16 * 16384 + i8;
    u16* pp = P16 + (size_t)bh * 16 * 16384 + i8;
    float run[8] = {};
    for (int c = 0; c < 16; ++c) {
        u16 ob[8];
#pragma unroll
        for (int j = 0; j < 8; ++j) { __hip_bfloat16 hv = __float2bfloat16(run[j]); ob[j] = *(u16*)&hv; }
        *(uint4*)(pp + (size_t)c * 16384) = *(uint4*)ob;
        uint4 tv = *(const uint4*)(tp + (size_t)c * 16384);
        const u16* tvp = (const u16*)&tv;
#pragma unroll
        for (int j = 0; j < 8; ++j) run[j] += bf2f(tvp[j]);
    }
}

// ---------------- chunked attention: out_c = qn_c . P_c + causal_intra ----------------
__global__ __launch_bounds__(256, 2) void attn2(
    const u16* __restrict__ qn, const u16* __restrict__ kn,
    const u16* __restrict__ vr, const u16* __restrict__ P16, u16* __restrict__ ao)
{
    __shared__ u16 KN[64][136];
    __shared__ u16 VT[128][72];
    __shared__ u16 SC[128][72];
    int tid = threadIdx.x, lane = tid & 63, w = tid >> 6;
    int c = blockIdx.x, bh = blockIdx.y;
    int b = bh >> 4, h = bh & 15;
    const int l15 = lane & 15, l4 = lane >> 4;
    size_t base = (size_t)bh * S * 128;
    const u16* Pp = P16 + (size_t)(bh * 16 + c) * 16384;

    bf16x8 qa[2][4];
#pragma unroll
    for (int m = 0; m < 2; ++m)
#pragma unroll
        for (int t = 0; t < 4; ++t) {
            int row = c * 128 + w * 32 + m * 16 + l15;
            qa[m][t] = *(const bf16x8*)(qn + base + (size_t)row * 128 + t * 32 + l4 * 8);
        }

    f32x4 acc[2][8] = {};

    // ---- inter: out += qn_c . P_c ----
#pragma unroll
    for (int pt = 0; pt < 2; ++pt) {
#pragma unroll
        for (int i = 0; i < 4; ++i) {
            int q = tid + i * 256;
            int r = q >> 3, c8 = q & 7;
            uint4 v = *(const uint4*)(Pp + (size_t)r * 128 + pt * 64 + c8 * 8);
            *(uint4*)(&VT[r][c8 * 8]) = v;
        }
        __syncthreads();
#pragma unroll
        for (int tt = 0; tt < 2; ++tt) {
            bf16x8 pb[8];
#pragma unroll
            for (int n = 0; n < 8; ++n)
                pb[n] = *(const bf16x8*)(&VT[n * 16 + l15][tt * 32 + l4 * 8]);
#pragma unroll
            for (int m = 0; m < 2; ++m)
#pragma unroll
                for (int n = 0; n < 8; ++n)
                    acc[m][n] = __builtin_amdgcn_mfma_f32_16x16x32_bf16(qa[m][pt * 2 + tt], pb[n], acc[m][n], 0, 0, 0);
        }
        __syncthreads();
    }

    // ---- intra: 2 causal k-tiles within the chunk ----
    for (int kt2 = 0; kt2 < 2; ++kt2) {
#pragma unroll
        for (int i = 0; i < 4; ++i) {
            int q = tid + i * 256;
            int r = q >> 4, c8 = q & 15;
            uint4 v = *(const uint4*)(kn + base + (size_t)(c * 128 + kt2 * 64 + r) * 128 + c8 * 8);
            *(uint4*)(&KN[r][c8 * 8]) = v;
        }
        // VT[d][k] <- v rows (transpose): 64 k x 128 d
#pragma unroll
        for (int i = 0; i < 4; ++i) {
            int q = tid + i * 256;
            int r = q >> 4, c16 = q & 15;
            uint4 v = *(const uint4*)(vr + base + (size_t)(c * 128 + kt2 * 64 + r) * 128 + c16 * 8);
            const u16* pv = (const u16*)&v;
#pragma unroll
            for (int j = 0; j < 8; ++j) VT[c16 * 8 + j][r] = pv[j];
        }
        __syncthreads();
        f32x4 sacc[2][4] = {};
#pragma unroll
        for (int t = 0; t < 4; ++t) {
            bf16x8 kb[4];
#pragma unroll
            for (int n = 0; n < 4; ++n)
                kb[n] = *(const bf16x8*)(&KN[n * 16 + l15][t * 32 + l4 * 8]);
#pragma unroll
            for (int m = 0; m < 2; ++m)
#pragma unroll
                for (int n = 0; n < 4; ++n)
                    sacc[m][n] = __builtin_amdgcn_mfma_f32_16x16x32_bf16(qa[m][t], kb[n], sacc[m][n], 0, 0, 0);
        }
#pragma unroll
        for (int m = 0; m < 2; ++m)
#pragma unroll
            for (int n = 0; n < 4; ++n)
#pragma unroll
                for (int r = 0; r < 4; ++r) {
                    int rowl = w * 32 + m * 16 + l4 * 4 + r;
                    int coll = n * 16 + l15;
                    int kl = kt2 * 64 + coll;
                    float val = (kl <= rowl) ? sacc[m][n][r] : 0.f;
                    __hip_bfloat16 hv = __float2bfloat16(val);
                    SC[rowl][coll] = *(u16*)&hv;
                }
#pragma unroll
        for (int t = 0; t < 2; ++t) {
            bf16x8 sa[2], vb[8];
#pragma unroll
            for (int m = 0; m < 2; ++m)
                sa[m] = *(const bf16x8*)(&SC[w * 32 + m * 16 + l15][t * 32 + l4 * 8]);
#pragma unroll
            for (int n = 0; n < 8; ++n)
                vb[n] = *(const bf16x8*)(&VT[n * 16 + l15][t * 32 + l4 * 8]);
#pragma unroll
            for (int m = 0; m < 2; ++m)
#pragma unroll
                for (int n = 0; n < 8; ++n)
                    acc[m][n] = __builtin_amdgcn_mfma_f32_16x16x32_bf16(sa[m], vb[n], acc[m][n], 0, 0, 0);
        }
        __syncthreads();
    }

#pragma unroll
    for (int m = 0; m < 2; ++m)
#pragma unroll
        for (int n = 0; n < 8; ++n)
#pragma unroll
            for (int r = 0; r < 4; ++r) {
                int srow = c * 128 + w * 32 + m * 16 + l4 * 4 + r;
                int d = n * 16 + l15;
                __hip_bfloat16 hv = __float2bfloat16(acc[m][n][r]);
                ao[(size_t)(b * S + srow) * D + h * 128 + d] = *(u16*)&hv;
            }
}

extern "C" void kernel_launch(void* const* d_in, const int* in_sizes, int n_in,
                              void* d_out, int out_size, void* d_ws, size_t ws_size,
                              hipStream_t stream)
{
    const float* hs = (const float*)d_in[0];
    const float* mask = (const float*)d_in[1];
    const int* pos = (const int*)d_in[2];
    const float* Wq = (const float*)d_in[3];
    const float* Wk = (const float*)d_in[4];
    const float* Wv = (const float*)d_in[5];
    const float* Wo = (const float*)d_in[6];
    const float* ncst = (const float*)d_in[7];
    float* out = (float*)d_out;

    char* ws = (char*)d_ws;
    size_t off = 0;
    auto alloc = [&](size_t bytes) {
        size_t o = off;
        off += (bytes + 255) & ~(size_t)255;
        return o;
    };
    u16* hs16 = (u16*)(ws + alloc((size_t)B * S * D * 2));
    u16* wqkv16 = (u16*)(ws + alloc((size_t)NQKV * D * 2));
    u16* wo16 = (u16*)(ws + alloc((size_t)D * D * 2));
    u16* tmpb = (u16*)(ws + alloc((size_t)B * S * NQKV * 2));
    u16* qn16 = (u16*)(ws + alloc((size_t)B * S * D * 2));
    u16* kn16 = (u16*)(ws + alloc((size_t)B * S * D * 2));
    u16* vr16 = (u16*)(ws + alloc((size_t)B * S * D * 2));
    float* sinb = (float*)(ws + alloc((size_t)B * S * 32 * 4));
    float* cosb = (float*)(ws + alloc((size_t)B * S * 32 * 4));
    float* keep = (float*)(ws + alloc((size_t)B * S * 4));
    float* counts = (float*)(ws + alloc((size_t)B * S * 4));
    float* expo = (float*)(ws + alloc(64));
    u16* ao16 = tmpb;
    u16* T16 = tmpb + (size_t)8388608;
    u16* P16 = tmpb + (size_t)16777216;

    cast_kernel<<<2048, 256, 0, stream>>>(hs, hs16, B * S * D / 4);
    castw_kernel<<<dim3(512, 4), 256, 0, stream>>>(
        Wq, Wk, Wv, Wo,
        wqkv16, wqkv16 + (size_t)D * D, wqkv16 + (size_t)2 * D * D, wo16, D * D / 4);
    prep_kernel<<<(B * S * 32 + 255) / 256, 256, 0, stream>>>(mask, pos, ncst, sinb, cosb, keep, expo);
    counts_kernel<<<B, 256, 0, stream>>>(keep, counts);

    // fused QKV projection (bf16 out): 256x384 tiles -> 16x16 = 256 blocks (1 round)
    gemm32<256, 384, 2, 3, 8, 6, 1><<<256, 512, 0, stream>>>(
        hs16, wqkv16, nullptr, tmpb, NQKV, D, NQKV / 384);

    postproc_all<<<(B * S * H) / 4, 256, 0, stream>>>(tmpb, qn16, kn16, vr16, sinb, cosb, keep, counts, expo);

    dim3 gc(S / 128, B * H);
    chunk_state<<<gc, 256, 0, stream>>>(kn16, vr16, T16);
    prefix_state<<<256, 256, 0, stream>>>(T16, P16);
    attn2<<<gc, 256, 0, stream>>>(qn16, kn16, vr16, P16, ao16);

    // output projection -> f32 out: 128x256 tiles -> 32x8 = 256 blocks (1 round)
    gemm32<128, 256, 1, 2, 4, 4, 0><<<256, 512, 0, stream>>>(
        ao16, wo16, out, nullptr, D, D, D / 256);
}